// Round 7
// baseline (230.950 us; speedup 1.0000x reference)
//
#include <hip/hip_runtime.h>

// Problem constants: B=16, DIM(C)=512, N=4096, H=8, HD=64, QKV rows = 8*129 = 1032.
#define NB 16
#define NC 512
#define NN 4096
#define NH 8

typedef __attribute__((ext_vector_type(8))) __bf16 bf16x8;
typedef __attribute__((ext_vector_type(4))) float f32x4;

__device__ __forceinline__ unsigned short f2bf(float f) {
    union { float f; unsigned u; } x; x.f = f;
    unsigned r = x.u + 0x7FFF + ((x.u >> 16) & 1);   // round-to-nearest-even
    return (unsigned short)(r >> 16);
}

// K0: repack Wv rows (head-interleaved) + Wp to bf16, gather bv.
__global__ void pack_kernel(const float* __restrict__ Wqkv, const float* __restrict__ bqkv,
                            const float* __restrict__ Wp,
                            unsigned short* __restrict__ Wv_bf, unsigned short* __restrict__ Wp_bf,
                            float* __restrict__ bv) {
    int t = blockIdx.x * 256 + threadIdx.x;          // 0 .. 512*512-1
    int j = t >> 9, c = t & 511;
    int h = j >> 6, d = j & 63;
    Wv_bf[t] = f2bf(Wqkv[((size_t)h * 129 + 65 + d) * 512 + c]);
    Wp_bf[t] = f2bf(Wp[t]);
    if (t < 512) bv[t] = bqkv[(t >> 6) * 129 + 65 + (t & 63)];
}

// K1: q c-chunk partials qP[cc][b][h][n] (fp32 exact; bias dropped: softmax shift-inv).
// Block: 64 c x 512 n. Thread owns an n-pair. Grid (8 n-chunks, 8 c-chunks, 16 b).
__global__ __launch_bounds__(256) void q_kernel(
        const float* __restrict__ x, const float* __restrict__ Wqkv,
        float* __restrict__ qP) {
    __shared__ float Ws[8][64];
    int n0 = blockIdx.x * 512, c0 = blockIdx.y * 64, b = blockIdx.z;
    int t = threadIdx.x;                             // 256
    for (int i = t; i < 512; i += 256)
        Ws[i >> 6][i & 63] = Wqkv[(size_t)(i >> 6) * (129 * 512) + c0 + (i & 63)];
    __syncthreads();

    float acc[8][2];
#pragma unroll
    for (int h = 0; h < 8; h++) { acc[h][0] = 0.f; acc[h][1] = 0.f; }

    const float* xb = x + ((size_t)b * NC + c0) * NN + n0;
#pragma unroll 4
    for (int c = 0; c < 64; c++) {
        float2 v = *((const float2*)(xb + (size_t)c * NN) + t);
#pragma unroll
        for (int h = 0; h < 8; h++) {
            float w = Ws[h][c];
            acc[h][0] += w * v.x;
            acc[h][1] += w * v.y;
        }
    }
#pragma unroll
    for (int h = 0; h < 8; h++) {
        float2 o; o.x = acc[h][0]; o.y = acc[h][1];
        *((float2*)(qP + ((size_t)(blockIdx.y * NB + b) * 8 + h) * NN + n0) + t) = o;
    }
}

// K2: softmax over N per (b,h) of q = sum of 8 c-chunk partials.
// Writes TRANSPOSED scores sT[b][n][h] (fp32).
__global__ void softmax_kernel(const float* __restrict__ qP, float* __restrict__ sT) {
    int bh = blockIdx.x;                 // b*8+h
    int b = bh >> 3, h = bh & 7;
    int t = threadIdx.x;                 // 256
    __shared__ float red[8];
    const float* qp = qP + (size_t)bh * NN;
    const size_t cstr = (size_t)NB * 8 * NN;         // c-chunk stride in qP
    float v[16];
    float mx = -1e30f;
#pragma unroll
    for (int i = 0; i < 16; i++) {
        int n = t + i * 256;
        float s = 0.f;
#pragma unroll
        for (int cb = 0; cb < 8; cb++) s += qp[cb * cstr + n];
        v[i] = s; mx = fmaxf(mx, s);
    }
#pragma unroll
    for (int o = 32; o; o >>= 1) mx = fmaxf(mx, __shfl_xor(mx, o));
    if ((t & 63) == 0) red[t >> 6] = mx;
    __syncthreads();
    mx = fmaxf(fmaxf(red[0], red[1]), fmaxf(red[2], red[3]));
    float s = 0.f;
#pragma unroll
    for (int i = 0; i < 16; i++) { v[i] = __expf(v[i] - mx); s += v[i]; }
#pragma unroll
    for (int o = 32; o; o >>= 1) s += __shfl_xor(s, o);
    __syncthreads();
    if ((t & 63) == 0) red[4 + (t >> 6)] = s;
    __syncthreads();
    float inv = 1.f / (red[4] + red[5] + red[6] + red[7]);
#pragma unroll
    for (int i = 0; i < 16; i++) {
        int n = t + i * 256;
        sT[((size_t)b * NN + n) * 8 + h] = v[i] * inv;
    }
}

// K3: partial xbar[slab][b][h][c] = sum_{n in 512-slab} sT[b][n][h] * x[b,c,n]  (fp32 x)
// Block: 32 c x 512 n, 4 waves; wave owns 8 c-rows; lane owns 8 consecutive n.
__global__ __launch_bounds__(256) void xbar_kernel(
        const float* __restrict__ x, const float* __restrict__ sT,
        float* __restrict__ xbarP) {
    __shared__ float red[4][8][64];
    int c0 = blockIdx.x * 32, sl = blockIdx.y, b = blockIdx.z;
    int t = threadIdx.x;
    int l = t & 63, w = t >> 6;
    int nsl0 = sl * 512;
    float s_[8][8];
    {
        const f32x4* sp = (const f32x4*)(sT + ((size_t)b * NN + nsl0 + l * 8) * 8);
#pragma unroll
        for (int j = 0; j < 8; j++) {
            f32x4 a = sp[2 * j], bq = sp[2 * j + 1];
            s_[j][0] = a[0]; s_[j][1] = a[1]; s_[j][2] = a[2]; s_[j][3] = a[3];
            s_[j][4] = bq[0]; s_[j][5] = bq[1]; s_[j][6] = bq[2]; s_[j][7] = bq[3];
        }
    }
    float acc[8][8];
#pragma unroll
    for (int r = 0; r < 8; r++)
#pragma unroll
        for (int h = 0; h < 8; h++) acc[r][h] = 0.f;

    const float* xr = x + ((size_t)b * NC + c0 + w * 8) * NN + nsl0 + l * 8;
#pragma unroll
    for (int r = 0; r < 8; r++) {
        float4 a0 = *(const float4*)(xr + (size_t)r * NN);
        float4 a1 = *(const float4*)(xr + (size_t)r * NN + 4);
        float xf[8] = {a0.x, a0.y, a0.z, a0.w, a1.x, a1.y, a1.z, a1.w};
#pragma unroll
        for (int j = 0; j < 8; j++)
#pragma unroll
            for (int h = 0; h < 8; h++) acc[r][h] += xf[j] * s_[j][h];
    }
#pragma unroll
    for (int r = 0; r < 8; r++)
#pragma unroll
        for (int h = 0; h < 8; h++) {
            float a = acc[r][h];
            a += __shfl_xor(a, 8);
            a += __shfl_xor(a, 16);
            a += __shfl_xor(a, 32);
            acc[r][h] = a;
        }
    if (l < 8) {
#pragma unroll
        for (int r = 0; r < 8; r++)
#pragma unroll
            for (int h = 0; h < 8; h++) red[w][l][r * 8 + h] = acc[r][h];
    }
    __syncthreads();
    {
        int idx = t & 63;                            // (r = idx>>3, h = idx&7)
        float v = 0.f;
#pragma unroll
        for (int res = 0; res < 8; res++) v += red[w][res][idx];
        int r = idx >> 3, h = idx & 7;
        xbarP[(((size_t)sl * NB + b) * 8 + h) * NC + c0 + w * 8 + r] = v;
    }
}

// K4: ctx[b][h*64+d] = Wk[h,d,:].xbar[b,h,:] + bk[h,d]   (sums 8 partial slabs)
__global__ void ctx_kernel(const float* __restrict__ xbarP, const float* __restrict__ Wqkv,
                           const float* __restrict__ bqkv, float* __restrict__ ctx) {
    int bh = blockIdx.x; int b = bh >> 3, h = bh & 7;
    int t = threadIdx.x;                                    // 256
    __shared__ float xb[512];
    for (int i = t; i < 512; i += 256) {
        float s = 0.f;
#pragma unroll
        for (int sl = 0; sl < 8; sl++) s += xbarP[(((size_t)sl * NB + b) * 8 + h) * NC + i];
        xb[i] = s;
    }
    __syncthreads();
    int d = t >> 2, sub = t & 3;
    const float* wk = Wqkv + ((size_t)h * 129 + 1 + d) * 512;
    float acc = 0.f;
    for (int i = sub * 4; i < 512; i += 16) {
        float4 w = *(const float4*)(wk + i);
        acc += w.x * xb[i] + w.y * xb[i + 1] + w.z * xb[i + 2] + w.w * xb[i + 3];
    }
    acc += __shfl_xor(acc, 1);
    acc += __shfl_xor(acc, 2);
    if (sub == 0) ctx[(size_t)b * NC + h * 64 + d] = acc + bqkv[h * 129 + 1 + d];
}

// K5: FUSED double GEMM per (b, 128-n tile):
//   phase A: M[512 j][128 n] = relu(Wv·xbf + bv)·ctx   (x staged fp32->bf16 in-register)
//            -> LDS Ms, laid out as 16 k-tiles of [n=128][k=32] (the Bs fragment format)
//   phase B: out[512 o][128 n] = Wp·M + bp              (no barriers, no staging)
// A-operands (Wv/Wp) are read directly from L2 with register double-buffering.
__global__ __launch_bounds__(512, 2) void fused_gemm_kernel(
    const unsigned short* __restrict__ Wv,    // [512][512] bf16
    const unsigned short* __restrict__ Wp,    // [512][512] bf16
    const float* __restrict__ x,              // [B][512][4096] fp32
    const float* __restrict__ bv,
    const float* __restrict__ bp,
    const float* __restrict__ ctx,            // [B][512]
    float* __restrict__ outp)                 // [B][512][4096] fp32
{
    __shared__ alignas(16) unsigned short Ms[16 * 128 * 32];  // 128 KB
    __shared__ alignas(16) unsigned short Bs[128 * 32];       // 8 KB, XOR-swizzled [n][k]
    int b = blockIdx.y, n0 = blockIdx.x * 128;
    int t = threadIdx.x;
    int lane = t & 63, wid = t >> 6;
    int wj = wid >> 1, wn = wid & 1;          // wave tile: 128 rows x 64 n
    int g = lane >> 4, col = lane & 15;
    int koff = g * 8;

    // staging coords (phase A): thread t handles x row c = t>>4, n = n8..n8+7
    int sc = t >> 4, sn8 = (t & 15) * 8;

    // ---------------- phase A ----------------
    f32x4 acc[8][4];
#pragma unroll
    for (int i = 0; i < 8; i++)
#pragma unroll
        for (int j = 0; j < 4; j++) { f32x4 z = {0.f, 0.f, 0.f, 0.f}; acc[i][j] = z; }

    bf16x8 afc[8], afn[8];
#pragma unroll
    for (int i = 0; i < 8; i++)
        afc[i] = *(const bf16x8*)(Wv + (size_t)(wj * 128 + i * 16 + col) * 512 + koff);

#pragma unroll 2
    for (int ks = 0; ks < 16; ks++) {
        int kk = ks * 32;
        // stage x-tile [c=32][n=128] -> Bs[n][k] (fp32 read, f2bf, XOR-swizzled scalar writes)
        {
            const float* xr = x + ((size_t)b * NC + kk + sc) * NN + n0 + sn8;
            float4 v0 = *(const float4*)(xr);
            float4 v1 = *(const float4*)(xr + 4);
            unsigned short xv[8] = {f2bf(v0.x), f2bf(v0.y), f2bf(v0.z), f2bf(v0.w),
                                    f2bf(v1.x), f2bf(v1.y), f2bf(v1.z), f2bf(v1.w)};
#pragma unroll
            for (int i = 0; i < 8; i++) {
                int nl = sn8 + i;
                int byte = nl * 64 + ((sc * 2) ^ (((nl >> 3) & 3) << 4));
                *(unsigned short*)((char*)Bs + byte) = xv[i];
            }
        }
        if (ks < 15) {
#pragma unroll
            for (int i = 0; i < 8; i++)
                afn[i] = *(const bf16x8*)(Wv + (size_t)(wj * 128 + i * 16 + col) * 512 + kk + 32 + koff);
        }
        __syncthreads();
        bf16x8 bfr[4];
#pragma unroll
        for (int j = 0; j < 4; j++) {
            int row = wn * 64 + j * 16 + col;
            int byte = row * 64 + ((koff * 2) ^ (((row >> 3) & 3) << 4));
            bfr[j] = *(const bf16x8*)((const char*)Bs + byte);
        }
#pragma unroll
        for (int i = 0; i < 8; i++)
#pragma unroll
            for (int j = 0; j < 4; j++)
                acc[i][j] = __builtin_amdgcn_mfma_f32_16x16x32_bf16(afc[i], bfr[j], acc[i][j], 0, 0, 0);
        __syncthreads();
#pragma unroll
        for (int i = 0; i < 8; i++) afc[i] = afn[i];
    }

    // phase A epilogue: relu(acc+bv)*ctx -> bf16 -> Ms[ktile][n][k]
#pragma unroll
    for (int i = 0; i < 8; i++) {
        int j0 = wj * 128 + i * 16 + g * 4;               // 4 consecutive M rows
        float4 bv4 = *(const float4*)(bv + j0);
        float4 cx4 = *(const float4*)(ctx + (size_t)b * NC + j0);
#pragma unroll
        for (int j = 0; j < 4; j++) {
            int n = wn * 64 + j * 16 + col;
            f32x4 a = acc[i][j];
            unsigned short h0 = f2bf(fmaxf(a[0] + bv4.x, 0.f) * cx4.x);
            unsigned short h1 = f2bf(fmaxf(a[1] + bv4.y, 0.f) * cx4.y);
            unsigned short h2 = f2bf(fmaxf(a[2] + bv4.z, 0.f) * cx4.z);
            unsigned short h3 = f2bf(fmaxf(a[3] + bv4.w, 0.f) * cx4.w);
            uint2 pk;
            pk.x = (unsigned)h0 | ((unsigned)h1 << 16);
            pk.y = (unsigned)h2 | ((unsigned)h3 << 16);
            *(uint2*)(Ms + (size_t)(j0 >> 5) * 4096 + n * 32 + (j0 & 31)) = pk;
        }
    }
    __syncthreads();

    // ---------------- phase B ----------------
#pragma unroll
    for (int i = 0; i < 8; i++)
#pragma unroll
        for (int j = 0; j < 4; j++) { f32x4 z = {0.f, 0.f, 0.f, 0.f}; acc[i][j] = z; }
#pragma unroll
    for (int i = 0; i < 8; i++)
        afc[i] = *(const bf16x8*)(Wp + (size_t)(wj * 128 + i * 16 + col) * 512 + koff);

#pragma unroll 2
    for (int ks = 0; ks < 16; ks++) {
        int kk = ks * 32;
        if (ks < 15) {
#pragma unroll
            for (int i = 0; i < 8; i++)
                afn[i] = *(const bf16x8*)(Wp + (size_t)(wj * 128 + i * 16 + col) * 512 + kk + 32 + koff);
        }
        bf16x8 bfr[4];
#pragma unroll
        for (int j = 0; j < 4; j++)
            bfr[j] = *(const bf16x8*)(Ms + (size_t)ks * 4096 + (wn * 64 + j * 16 + col) * 32 + koff);
#pragma unroll
        for (int i = 0; i < 8; i++)
#pragma unroll
            for (int j = 0; j < 4; j++)
                acc[i][j] = __builtin_amdgcn_mfma_f32_16x16x32_bf16(afc[i], bfr[j], acc[i][j], 0, 0, 0);
#pragma unroll
        for (int i = 0; i < 8; i++) afc[i] = afn[i];
    }

    // phase B epilogue: out = acc + bp (fp32)
#pragma unroll
    for (int i = 0; i < 8; i++) {
        int o0 = wj * 128 + i * 16 + g * 4;
        float4 bp4 = *(const float4*)(bp + o0);
#pragma unroll
        for (int j = 0; j < 4; j++) {
            int n = n0 + wn * 64 + j * 16 + col;
            f32x4 a = acc[i][j];
            float* op = outp + ((size_t)b * NC + o0) * NN + n;
            op[0]              = a[0] + bp4.x;
            op[NN]             = a[1] + bp4.y;
            op[2 * (size_t)NN] = a[2] + bp4.z;
            op[3 * (size_t)NN] = a[3] + bp4.w;
        }
    }
}

extern "C" void kernel_launch(void* const* d_in, const int* in_sizes, int n_in,
                              void* d_out, int out_size, void* d_ws, size_t ws_size,
                              hipStream_t stream) {
    const float* x    = (const float*)d_in[0];
    const float* Wqkv = (const float*)d_in[1];
    const float* bqkv = (const float*)d_in[2];
    const float* Wp   = (const float*)d_in[3];
    const float* bp   = (const float*)d_in[4];
    float* outp = (float*)d_out;

    // ws layout (no d_out aliasing anymore; ~22 MB total)
    char* ws = (char*)d_ws;
    float* sT    = (float*)(ws);                                      // 2 MB
    float* qP    = (float*)(ws + 2097152);                            // 16 MB
    float* xbarP = (float*)(ws + 18874368);                           // 2 MB
    float* ctx   = (float*)(ws + 20971520);                           // 32 KB
    unsigned short* Wv_bf = (unsigned short*)(ws + 20971520 + 32768);            // 512 KB
    unsigned short* Wp_bf = (unsigned short*)(ws + 20971520 + 32768 + 524288);   // 512 KB
    float* bv    = (float*)(ws + 20971520 + 32768 + 1048576);         // 2 KB

    pack_kernel<<<dim3(1024), 256, 0, stream>>>(Wqkv, bqkv, Wp, Wv_bf, Wp_bf, bv);
    q_kernel<<<dim3(8, 8, 16), 256, 0, stream>>>(x, Wqkv, qP);
    softmax_kernel<<<dim3(128), 256, 0, stream>>>(qP, sT);
    xbar_kernel<<<dim3(16, 8, 16), 256, 0, stream>>>(x, sT, xbarP);
    ctx_kernel<<<dim3(128), 256, 0, stream>>>(xbarP, Wqkv, bqkv, ctx);
    fused_gemm_kernel<<<dim3(32, 16), 512, 0, stream>>>(Wv_bf, Wp_bf, x, bv, bp, ctx, outp);
}